// Round 4
// baseline (107.061 us; speedup 1.0000x reference)
//
#include <hip/hip_runtime.h>

#define NPTS 2048
#define QC 32                   // gt chunks per sample
#define G  (NPTS / QC)          // 64 gt points per chunk
#define RP 8                    // points per thread in pm_setup / pm_partial
#define HARD_COS 0.9914448613738104f  // cos(7.5 deg); ang>15deg <=> clipped |dot| < this
#define META_FLOATS 8
#define PRED_OFF 1024           // float offset of pred_rot in ws (16B aligned)

// ws layout:
//   meta  float [B][8]        at 0          [0]=valid, [1]=use_closest
//   pred_rot float4[B][NPTS]  at PRED_OFF   {ppx,ppy,ppz,0}
//   gt_rot   float4[B][NPTS]  at gt_off     {gx,gy,gz,|g|^2}
//   cand     float2[B][QC][NPTS] at cand_off  {best d, best q} per chunk

// grid (2, B): side 0 rotates pred cloud, side 1 rotates gt cloud (+|g|^2).
// Each block redundantly derives cls + its quaternion rotmat (wave-uniform).
__global__ __launch_bounds__(256) void pm_setup(const float* __restrict__ pred,
                                                const float* __restrict__ tgt,
                                                const float* __restrict__ wgt,
                                                const float* __restrict__ sym,
                                                const float* __restrict__ points,
                                                float* __restrict__ ws,
                                                float* __restrict__ out,
                                                int B, int C, int gt_off) {
    const int b = blockIdx.y;
    const int side = blockIdx.x;

    int cls = 0; float valid = 0.0f;
    for (int c = 0; c < C; ++c) {
        if (wgt[b * 4 * C + c * 4] > 0.0f) { cls = c; valid = 1.0f; break; }
    }

    const float* q = (side == 0 ? pred : tgt) + b * 4 * C + cls * 4;
    const float w = q[0], x = q[1], y = q[2], z = q[3];
    const float m0 = 1.f - 2.f * (y * y + z * z);
    const float m1 = 2.f * (x * y - z * w);
    const float m2 = 2.f * (x * z + y * w);
    const float m3 = 2.f * (x * y + z * w);
    const float m4 = 1.f - 2.f * (x * x + z * z);
    const float m5 = 2.f * (y * z - x * w);
    const float m6 = 2.f * (x * z - y * w);
    const float m7 = 2.f * (y * z + x * w);
    const float m8 = 1.f - 2.f * (x * x + y * y);

    const float* pts = points + (size_t)cls * NPTS * 3;
    float4* dst = (float4*)(ws + (side == 0 ? PRED_OFF : gt_off)) + (size_t)b * NPTS;
    const int tid = threadIdx.x;
    if (valid != 0.0f) {
#pragma unroll
        for (int r = 0; r < RP; ++r) {
            int i = r * 256 + tid;
            float px = pts[i * 3 + 0], py = pts[i * 3 + 1], pz = pts[i * 3 + 2];
            float ax = m0 * px + m1 * py + m2 * pz;
            float ay = m3 * px + m4 * py + m5 * pz;
            float az = m6 * px + m7 * py + m8 * pz;
            float ww = (side == 0) ? 0.0f : (ax * ax + ay * ay + az * az);
            dst[i] = make_float4(ax, ay, az, ww);
        }
    }

    if (side == 0 && tid == 0) {
        const float* qp = pred + b * 4 * C + cls * 4;
        const float* qg = tgt  + b * 4 * C + cls * 4;
        float dot = fabsf(qp[0] * qg[0] + qp[1] * qg[1] + qp[2] * qg[2] + qp[3] * qg[3]);
        dot = fminf(fmaxf(dot, 0.0f), 1.0f);
        float uc = (sym[cls] > 0.0f && dot < HARD_COS) ? 1.0f : 0.0f;
        ws[b * META_FLOATS + 0] = valid;
        ws[b * META_FLOATS + 1] = uc;
        if (b == 0) out[0] = 0.0f;   // harness poisons d_out; final atomically adds
    }
}

// grid (QC, B): each block scans one gt-chunk (G points) against ALL preds,
// RP preds per thread. Writes per-chunk {d, q} winner to cand[b][qc][p].
__global__ __launch_bounds__(256) void pm_partial(float* __restrict__ ws,
                                                  int gt_off, int cand_off) {
    const int b  = blockIdx.y;
    const int qc = blockIdx.x;
    if (ws[b * META_FLOATS + 0] == 0.0f || ws[b * META_FLOATS + 1] == 0.0f) return;

    const float4* pred_rot = (const float4*)(ws + PRED_OFF) + (size_t)b * NPTS;
    const float4* gt_rot   = (const float4*)(ws + gt_off)   + (size_t)b * NPTS;
    const int tid = threadIdx.x;

    __shared__ float4 gt[G];
    if (tid < G) gt[tid] = gt_rot[qc * G + tid];
    __syncthreads();

    float nx[RP], ny[RP], nz[RP], bd[RP];
    int bi[RP];
#pragma unroll
    for (int r = 0; r < RP; ++r) {
        float4 pp = pred_rot[r * 256 + tid];
        nx[r] = -2.0f * pp.x; ny[r] = -2.0f * pp.y; nz[r] = -2.0f * pp.z;
        bd[r] = 3.4e38f; bi[r] = 0;
    }

#pragma unroll 4
    for (int j = 0; j < G; ++j) {
        float4 g = gt[j];
#pragma unroll
        for (int r = 0; r < RP; ++r) {
            float d = __fmaf_rn(nx[r], g.x,
                      __fmaf_rn(ny[r], g.y,
                      __fmaf_rn(nz[r], g.z, g.w)));
            if (d < bd[r]) { bd[r] = d; bi[r] = j; }   // strict <: first min
        }
    }

    float2* cand = (float2*)(ws + cand_off) + ((size_t)b * QC + qc) * NPTS;
#pragma unroll
    for (int r = 0; r < RP; ++r) {
        int p = r * 256 + tid;
        cand[p] = make_float2(bd[r], (float)(qc * G + bi[r]));   // coalesced
    }
}

__device__ __forceinline__ float smooth_l1(float x) {
    float ax = fabsf(x);
    return (ax < 1.0f) ? 0.5f * x * x : ax - 0.5f;
}

// grid (NPTS/256, B): resolve QC stored {d,q} winners per pred (bit-identical d
// values from pm_partial; strict < in ascending qc == global first-min),
// single gt gather, smooth-L1, block reduce, atomicAdd.
__global__ __launch_bounds__(256) void pm_final(float* __restrict__ ws,
                                                float* __restrict__ out,
                                                int gt_off, int cand_off,
                                                float inv_bp) {
    __shared__ float partial[4];
    const int b = blockIdx.y;
    const int tid = threadIdx.x;
    float acc = 0.0f;

    if (ws[b * META_FLOATS + 0] != 0.0f) {
        const float4* pred_rot = (const float4*)(ws + PRED_OFF) + (size_t)b * NPTS;
        const float4* gt_rot   = (const float4*)(ws + gt_off)   + (size_t)b * NPTS;
        const int p = blockIdx.x * 256 + tid;
        float4 pp = pred_rot[p];
        float4 g;
        if (ws[b * META_FLOATS + 1] != 0.0f) {
            const float2* cand = (const float2*)(ws + cand_off) + (size_t)b * QC * NPTS + p;
            float bd = 3.4e38f; int bq = 0;
#pragma unroll
            for (int qc = 0; qc < QC; ++qc) {
                float2 cq = cand[(size_t)qc * NPTS];   // coalesced per qc
                if (cq.x < bd) { bd = cq.x; bq = (int)cq.y; }
            }
            g = gt_rot[bq];
        } else {
            g = gt_rot[p];
        }
        acc = smooth_l1(pp.x - g.x) + smooth_l1(pp.y - g.y) + smooth_l1(pp.z - g.z);
    }

    for (int off = 32; off > 0; off >>= 1) acc += __shfl_down(acc, off);
    if ((tid & 63) == 0) partial[tid >> 6] = acc;
    __syncthreads();
    if (tid == 0) {
        float s = partial[0] + partial[1] + partial[2] + partial[3];
        atomicAdd(out, s * inv_bp);
    }
}

extern "C" void kernel_launch(void* const* d_in, const int* in_sizes, int n_in,
                              void* d_out, int out_size, void* d_ws, size_t ws_size,
                              hipStream_t stream) {
    const float* pred = (const float*)d_in[0];
    const float* tgt  = (const float*)d_in[1];
    const float* wgt  = (const float*)d_in[2];
    const float* pts  = (const float*)d_in[3];
    const float* sym  = (const float*)d_in[4];
    float* out = (float*)d_out;
    float* ws  = (float*)d_ws;

    const int C = in_sizes[4];
    const int B = in_sizes[0] / (4 * C);

    const int gt_off   = PRED_OFF + B * NPTS * 4;            // floats
    const int cand_off = gt_off   + B * NPTS * 4;            // floats

    dim3 gridS(2, B);
    pm_setup<<<gridS, 256, 0, stream>>>(pred, tgt, wgt, sym, pts, ws, out, B, C, gt_off);
    dim3 gridP(QC, B);
    pm_partial<<<gridP, 256, 0, stream>>>(ws, gt_off, cand_off);
    dim3 gridF(NPTS / 256, B);
    pm_final<<<gridF, 256, 0, stream>>>(ws, out, gt_off, cand_off,
                                        1.0f / (float)(B * NPTS));
}

// Round 5
// 104.793 us; speedup vs baseline: 1.0216x; 1.0216x over previous
//
#include <hip/hip_runtime.h>

#define NPTS 2048
#define QC 32                   // gt chunks per sample
#define G  (NPTS / QC)          // 64 gt points per chunk
#define RP 8                    // pred points per thread in pm_scan
#define HARD_COS 0.9914448613738104f  // cos(7.5 deg); ang>15deg <=> clipped |dot| < this

// ws layout: cand float2[B][QC][NPTS] at offset 0 -> {best d, best q} per chunk.
// Everything else (cls/valid/uc, rotation matrices, rotated points) is
// re-derived per block from the raw inputs: wave-uniform and cheap (~100 ops),
// which deletes the setup dispatch and all pred_rot/gt_rot global traffic.

struct Meta { int cls; bool valid; bool uc; };

__device__ __forceinline__ Meta get_meta(const float* __restrict__ pred,
                                         const float* __restrict__ tgt,
                                         const float* __restrict__ wgt,
                                         const float* __restrict__ sym,
                                         int b, int C) {
    Meta m; m.cls = 0; m.valid = false;
    for (int c = 0; c < C; ++c) {
        if (wgt[b * 4 * C + c * 4] > 0.0f) { m.cls = c; m.valid = true; break; }
    }
    const float* qp = pred + b * 4 * C + m.cls * 4;
    const float* qg = tgt  + b * 4 * C + m.cls * 4;
    float dot = fabsf(qp[0] * qg[0] + qp[1] * qg[1] + qp[2] * qg[2] + qp[3] * qg[3]);
    dot = fminf(fmaxf(dot, 0.0f), 1.0f);
    m.uc = m.valid && (sym[m.cls] > 0.0f) && (dot < HARD_COS);
    return m;
}

__device__ __forceinline__ void quat_rotmat(const float* __restrict__ q, float* m) {
    float w = q[0], x = q[1], y = q[2], z = q[3];
    m[0] = 1.f - 2.f * (y * y + z * z);
    m[1] = 2.f * (x * y - z * w);
    m[2] = 2.f * (x * z + y * w);
    m[3] = 2.f * (x * y + z * w);
    m[4] = 1.f - 2.f * (x * x + z * z);
    m[5] = 2.f * (y * z - x * w);
    m[6] = 2.f * (x * z - y * w);
    m[7] = 2.f * (y * z + x * w);
    m[8] = 1.f - 2.f * (x * x + y * y);
}

__device__ __forceinline__ float smooth_l1(float x) {
    float ax = fabsf(x);
    return (ax < 1.0f) ? 0.5f * x * x : ax - 0.5f;
}

// grid (QC, B): one block per (gt-chunk, sample). Rotates its 64 gt points to
// LDS, its RP=8 pred points to registers, scans, writes {d, q} winners.
__global__ __launch_bounds__(256) void pm_scan(const float* __restrict__ pred,
                                               const float* __restrict__ tgt,
                                               const float* __restrict__ wgt,
                                               const float* __restrict__ sym,
                                               const float* __restrict__ points,
                                               float* __restrict__ ws,
                                               float* __restrict__ out, int C) {
    const int b  = blockIdx.y;
    const int qc = blockIdx.x;
    const int tid = threadIdx.x;

    if (b == 0 && qc == 0 && tid == 0) out[0] = 0.0f;  // d_out is poisoned 0xAA

    Meta mt = get_meta(pred, tgt, wgt, sym, b, C);
    if (!mt.valid || !mt.uc) return;

    float Rp[9], Rg[9];
    quat_rotmat(pred + b * 4 * C + mt.cls * 4, Rp);
    quat_rotmat(tgt  + b * 4 * C + mt.cls * 4, Rg);
    const float* pts = points + (size_t)mt.cls * NPTS * 3;

    __shared__ float4 gt[G];
    if (tid < G) {
        int i = qc * G + tid;
        float x = pts[i * 3 + 0], y = pts[i * 3 + 1], z = pts[i * 3 + 2];
        float ax = Rg[0] * x + Rg[1] * y + Rg[2] * z;
        float ay = Rg[3] * x + Rg[4] * y + Rg[5] * z;
        float az = Rg[6] * x + Rg[7] * y + Rg[8] * z;
        gt[tid] = make_float4(ax, ay, az, ax * ax + ay * ay + az * az);
    }

    float nx[RP], ny[RP], nz[RP], bd[RP];
    int bi[RP];
#pragma unroll
    for (int r = 0; r < RP; ++r) {
        int p = r * 256 + tid;
        float x = pts[p * 3 + 0], y = pts[p * 3 + 1], z = pts[p * 3 + 2];
        float ppx = Rp[0] * x + Rp[1] * y + Rp[2] * z;
        float ppy = Rp[3] * x + Rp[4] * y + Rp[5] * z;
        float ppz = Rp[6] * x + Rp[7] * y + Rp[8] * z;
        nx[r] = -2.0f * ppx; ny[r] = -2.0f * ppy; nz[r] = -2.0f * ppz;
        bd[r] = 3.4e38f; bi[r] = 0;
    }
    __syncthreads();

#pragma unroll 4
    for (int j = 0; j < G; ++j) {
        float4 g = gt[j];
#pragma unroll
        for (int r = 0; r < RP; ++r) {
            float d = __fmaf_rn(nx[r], g.x,
                      __fmaf_rn(ny[r], g.y,
                      __fmaf_rn(nz[r], g.z, g.w)));
            if (d < bd[r]) { bd[r] = d; bi[r] = j; }   // strict <: first min
        }
    }

    float2* cand = (float2*)ws + ((size_t)b * QC + qc) * NPTS;
#pragma unroll
    for (int r = 0; r < RP; ++r) {
        int p = r * 256 + tid;
        cand[p] = make_float2(bd[r], (float)(qc * G + bi[r]));   // coalesced
    }
}

// grid (NPTS/256, B): resolve the QC stored {d,q} winners per pred point
// (bit-identical d's from pm_scan; strict < in ascending qc == global
// first-min), one raw-point gather + rotate, smooth-L1, reduce, atomicAdd.
__global__ __launch_bounds__(256) void pm_final(const float* __restrict__ pred,
                                                const float* __restrict__ tgt,
                                                const float* __restrict__ wgt,
                                                const float* __restrict__ sym,
                                                const float* __restrict__ points,
                                                const float* __restrict__ ws,
                                                float* __restrict__ out,
                                                int C, float inv_bp) {
    __shared__ float partial[4];
    const int b = blockIdx.y;
    const int tid = threadIdx.x;
    float acc = 0.0f;

    Meta mt = get_meta(pred, tgt, wgt, sym, b, C);
    if (mt.valid) {
        float Rp[9], Rg[9];
        quat_rotmat(pred + b * 4 * C + mt.cls * 4, Rp);
        quat_rotmat(tgt  + b * 4 * C + mt.cls * 4, Rg);
        const float* pts = points + (size_t)mt.cls * NPTS * 3;
        const int p = blockIdx.x * 256 + tid;

        float x = pts[p * 3 + 0], y = pts[p * 3 + 1], z = pts[p * 3 + 2];
        float ppx = Rp[0] * x + Rp[1] * y + Rp[2] * z;
        float ppy = Rp[3] * x + Rp[4] * y + Rp[5] * z;
        float ppz = Rp[6] * x + Rp[7] * y + Rp[8] * z;

        int q = p;                                  // direct path: matched = p_gt[p]
        if (mt.uc) {
            const float2* cand = (const float2*)ws + (size_t)b * QC * NPTS + p;
            float bd = 3.4e38f; q = 0;
#pragma unroll
            for (int c = 0; c < QC; ++c) {
                float2 cq = cand[(size_t)c * NPTS];  // coalesced per chunk
                if (cq.x < bd) { bd = cq.x; q = (int)cq.y; }
            }
        }
        float qx = pts[q * 3 + 0], qy = pts[q * 3 + 1], qz = pts[q * 3 + 2];
        float gx = Rg[0] * qx + Rg[1] * qy + Rg[2] * qz;
        float gy = Rg[3] * qx + Rg[4] * qy + Rg[5] * qz;
        float gz = Rg[6] * qx + Rg[7] * qy + Rg[8] * qz;
        acc = smooth_l1(ppx - gx) + smooth_l1(ppy - gy) + smooth_l1(ppz - gz);
    }

    for (int off = 32; off > 0; off >>= 1) acc += __shfl_down(acc, off);
    if ((tid & 63) == 0) partial[tid >> 6] = acc;
    __syncthreads();
    if (tid == 0) {
        float s = partial[0] + partial[1] + partial[2] + partial[3];
        atomicAdd(out, s * inv_bp);
    }
}

extern "C" void kernel_launch(void* const* d_in, const int* in_sizes, int n_in,
                              void* d_out, int out_size, void* d_ws, size_t ws_size,
                              hipStream_t stream) {
    const float* pred = (const float*)d_in[0];
    const float* tgt  = (const float*)d_in[1];
    const float* wgt  = (const float*)d_in[2];
    const float* pts  = (const float*)d_in[3];
    const float* sym  = (const float*)d_in[4];
    float* out = (float*)d_out;
    float* ws  = (float*)d_ws;

    const int C = in_sizes[4];
    const int B = in_sizes[0] / (4 * C);

    dim3 gridS(QC, B);
    pm_scan<<<gridS, 256, 0, stream>>>(pred, tgt, wgt, sym, pts, ws, out, C);
    dim3 gridF(NPTS / 256, B);
    pm_final<<<gridF, 256, 0, stream>>>(pred, tgt, wgt, sym, pts, ws, out,
                                        C, 1.0f / (float)(B * NPTS));
}